// Round 12
// baseline (735.998 us; speedup 1.0000x reference)
//
#include <hip/hip_runtime.h>
#include <hip/hip_bf16.h>

// QuantizedLinear: out[8192,11008] = x[8192,4096] @ dequant(W)^T
// Round 12: full register double-buffer of fragments (we have ~700 spare
// regs/wave at the LDS-capped 2 waves/SIMD). One phase + ONE barrier per
// K-tile: {stage u+2; 64 MFMA on cur regs with all 24 next-tile ds_reads
// interleaved into the first half; VMCNT0+LGKM0 (both free by distance); BAR}.
// launch_bounds (512,1): the old (512,2) 128-reg cap would spill.

#define IN_F   4096
#define OUT_F  11008
#define M_DIM  8192
#define NGROUP 32

typedef __bf16 bf16x8 __attribute__((ext_vector_type(8)));
typedef float  f32x4  __attribute__((ext_vector_type(4)));
typedef unsigned short u16;
typedef u16 u16x8v __attribute__((ext_vector_type(8)));

__device__ __forceinline__ u16 f2bf(float f) {
  union { float f; unsigned u; } v; v.f = f;
  unsigned u = v.u;
  return (u16)((u + 0x7fffu + ((u >> 16) & 1u)) >> 16);  // RNE
}

__device__ __forceinline__ void gload_lds16(const void* gsrc, void* ldst) {
  __builtin_amdgcn_global_load_lds(
      (const __attribute__((address_space(1))) void*)gsrc,
      (__attribute__((address_space(3))) void*)ldst, 16, 0, 0);
}

// ---------------- dequant: packed 4-bit -> bf16 W[out][in] -----------------
__global__ __launch_bounds__(256) void dequant_w(const int* __restrict__ qw,
                                                 const int* __restrict__ qz,
                                                 const float* __restrict__ sc,
                                                 u16* __restrict__ W) {
  const int total = (IN_F / 2) * OUT_F / 4;  // int4 chunks
  int stride = gridDim.x * blockDim.x;
  for (int idx = blockIdx.x * blockDim.x + threadIdx.x; idx < total; idx += stride) {
    int j = idx << 2;
    int o = j >> 11;
    int g = (j >> 6) & 31;
    float z = (float)qz[(o << 5) + g];
    float s = sc[(o << 5) + g];
    int4 q = ((const int4*)qw)[idx];
    int qs0 = q.x, qs1 = q.y, qs2 = q.z, qs3 = q.w;
    u16x8v w;
    w[0] = f2bf(((float)(qs0 & 15) - z) * s);
    w[1] = f2bf(((float)((qs0 >> 4) & 15) - z) * s);
    w[2] = f2bf(((float)(qs1 & 15) - z) * s);
    w[3] = f2bf(((float)((qs1 >> 4) & 15) - z) * s);
    w[4] = f2bf(((float)(qs2 & 15) - z) * s);
    w[5] = f2bf(((float)((qs2 >> 4) & 15) - z) * s);
    w[6] = f2bf(((float)(qs3 & 15) - z) * s);
    w[7] = f2bf(((float)((qs3 >> 4) & 15) - z) * s);
    ((u16x8v*)W)[idx] = w;
  }
}

// ---------------- x fp32 -> bf16 -------------------------------------------
__global__ __launch_bounds__(256) void cvt_x(const float* __restrict__ x,
                                             u16* __restrict__ Xb) {
  const int total = M_DIM * IN_F / 8;
  int stride = gridDim.x * blockDim.x;
  for (int idx = blockIdx.x * blockDim.x + threadIdx.x; idx < total; idx += stride) {
    float4 a = ((const float4*)x)[idx * 2];
    float4 b = ((const float4*)x)[idx * 2 + 1];
    u16x8v v;
    v[0] = f2bf(a.x); v[1] = f2bf(a.y); v[2] = f2bf(a.z); v[3] = f2bf(a.w);
    v[4] = f2bf(b.x); v[5] = f2bf(b.y); v[6] = f2bf(b.z); v[7] = f2bf(b.w);
    ((u16x8v*)Xb)[idx] = v;
  }
}

// ---------------- 256x256 bf16 GEMM, 1 barrier/K-tile: C = A * B^T ---------
// 8 waves 2Mx4N, wave tile 128x64 contiguous. Fragments fully register-
// double-buffered (aC/bC vs aN/bN); LDS buffers ping-pong by tile parity:
// tile u: stages (u+2)->buf[u&1], reads tile u+1 frags <- buf[(u&1)^1].
// Cross-wave ledger: reads of buf c^1 covered by tile u-1's VMCNT0+BAR
// (stages issued in u-1 drained there); stage-WAR into buf c covered by
// tile u-1's LGKM0+BAR (tile u-1's preloads were the last readers).

#define BAR       __builtin_amdgcn_s_barrier()
#define SCHED0    __builtin_amdgcn_sched_barrier(0)
#define LGKM0     asm volatile("s_waitcnt lgkmcnt(0)" ::: "memory")
#define VMCNT0    asm volatile("s_waitcnt vmcnt(0)" ::: "memory")
#define PRIO(p)   __builtin_amdgcn_s_setprio(p)

__global__ __launch_bounds__(512, 1) void gemm256(const u16* __restrict__ A,
                                                  const u16* __restrict__ B,
                                                  float* __restrict__ C) {
  constexpr int K = IN_F, N = OUT_F;
  constexpr int NT = K / 64;  // 64 K-tiles
  __shared__ __align__(16) u16 sA[2][256 * 64];
  __shared__ __align__(16) u16 sB[2][256 * 64];

  const int NTN = OUT_F / 256;           // 43
  const int NWG = (M_DIM / 256) * NTN;   // 1376 (divisible by 8)
  int bid = blockIdx.x;
  int wg  = (bid & 7) * (NWG / 8) + (bid >> 3);  // bijective XCD swizzle
  int tm = wg / NTN, tn = wg - tm * NTN;
  int m0 = tm * 256, n0 = tn * 256;

  int tid  = threadIdx.x;
  int lane = tid & 63;
  int wave = tid >> 6;
  int wr = wave >> 2, wc = wave & 3;

  // staging: thread covers row (tid>>3) (+64/128/192), phys 16B slot tid&7.
  // phys slot s at row r holds global col-slot s^(r&7)  (involution).
  int rstage = tid >> 3;                               // 0..63
  int gslot  = ((tid & 7) ^ (rstage & 7)) << 3;        // global col elem
  int ldsoff = rstage * 64 + ((tid & 7) << 3);         // linear LDS elem
  const u16* Ag = A + (size_t)(m0 + rstage) * K + gslot;
  const u16* Bg = B + (size_t)(n0 + rstage) * K + gslot;

  // full-tile stage: 4 A-gloads + 4 B-gloads (64 rows each)
#define STAGE_AB(cb, kt) do {                                     \
    const u16* _ga = Ag + (kt) * 64;                              \
    const u16* _gb = Bg + (kt) * 64;                              \
    u16* _la = sA[cb] + ldsoff;                                   \
    u16* _lb = sB[cb] + ldsoff;                                   \
    gload_lds16(_ga, _la);                                        \
    gload_lds16(_ga + (size_t)64 * K, _la + 64 * 64);             \
    gload_lds16(_ga + (size_t)128 * K, _la + 128 * 64);           \
    gload_lds16(_ga + (size_t)192 * K, _la + 192 * 64);           \
    gload_lds16(_gb, _lb);                                        \
    gload_lds16(_gb + (size_t)64 * K, _lb + 64 * 64);             \
    gload_lds16(_gb + (size_t)128 * K, _lb + 128 * 64);           \
    gload_lds16(_gb + (size_t)192 * K, _lb + 192 * 64);           \
  } while (0)

  // fragment reads: lane reads row base+(lane&15), k-quad q=lane>>4, slice ks.
  // phys 16B slot = (ks*4+q) ^ (lane&7)  (all row bases are multiples of 16)
  int q8  = lane >> 4;
  int sl0 = ((q8 ^ (lane & 7)) << 3);            // ks=0, elems
  int sl1 = (((q8 | 4) ^ (lane & 7)) << 3);      // ks=1
  int abase = (wr * 128 + (lane & 15)) * 64;     // wave rows wr*128..+127
  int bbase = (wc * 64 + (lane & 15)) * 64;      // wave cols wc*64..+63

  // register double-buffer: 16+8 frags per set
  bf16x8 aC[16], bC[8], aN[16], bN[8];
  f32x4 acc[8][4] = {};

#define LDALL(cb, AA, BB) do {                                    \
    const u16* _pa = sA[cb] + abase;                              \
    const u16* _pb = sB[cb] + bbase;                              \
    _Pragma("unroll") for (int mf = 0; mf < 8; mf++) {            \
      AA[mf*2+0] = *(const bf16x8*)(_pa + mf * 1024 + sl0);       \
      AA[mf*2+1] = *(const bf16x8*)(_pa + mf * 1024 + sl1);       \
    }                                                             \
    _Pragma("unroll") for (int nf = 0; nf < 4; nf++) {            \
      BB[nf*2+0] = *(const bf16x8*)(_pb + nf * 1024 + sl0);       \
      BB[nf*2+1] = *(const bf16x8*)(_pb + nf * 1024 + sl1);       \
    }                                                             \
  } while (0)

  // one K-tile: stage u+2 -> buf c; 64 MFMA (ks-outer, dep distance 32) on
  // CUR regs; all 24 next-tile reads interleaved into the ks=0 pass.
#define TILE(c, u, CA, CB, NA, NB) do {                           \
    STAGE_AB(c, ((u) + 2) & (NT - 1));                            \
    const u16* _ra = sA[(c) ^ 1] + abase;                         \
    const u16* _rb = sB[(c) ^ 1] + bbase;                         \
    PRIO(1);                                                      \
    _Pragma("unroll") for (int mf = 0; mf < 8; mf++) {            \
      _Pragma("unroll") for (int nf = 0; nf < 4; nf++)            \
        acc[mf][nf] = __builtin_amdgcn_mfma_f32_16x16x32_bf16(    \
            CA[mf*2+0], CB[nf*2+0], acc[mf][nf], 0, 0, 0);        \
      NA[mf*2+0] = *(const bf16x8*)(_ra + mf * 1024 + sl0);       \
      NA[mf*2+1] = *(const bf16x8*)(_ra + mf * 1024 + sl1);       \
      if (mf < 4) {                                               \
        NB[mf*2+0] = *(const bf16x8*)(_rb + mf * 1024 + sl0);     \
        NB[mf*2+1] = *(const bf16x8*)(_rb + mf * 1024 + sl1);     \
      }                                                           \
    }                                                             \
    _Pragma("unroll") for (int mf = 0; mf < 8; mf++)              \
      _Pragma("unroll") for (int nf = 0; nf < 4; nf++)            \
        acc[mf][nf] = __builtin_amdgcn_mfma_f32_16x16x32_bf16(    \
            CA[mf*2+1], CB[nf*2+1], acc[mf][nf], 0, 0, 0);        \
    PRIO(0);                                                      \
    VMCNT0; LGKM0; BAR;                                           \
  } while (0)

  // prologue: stage t0 -> buf0; drain+bar; preload cur <- buf0; stage t1 ->
  // buf1; drain stages (one-time exposed ~900cy) + drain preloads; bar.
  STAGE_AB(0, 0);
  VMCNT0; BAR;
  SCHED0;
  asm volatile("" ::: "memory");
  LDALL(0, aC, bC);
  STAGE_AB(1, 1);
  VMCNT0; LGKM0; BAR;

#pragma unroll 1
  for (int u = 0; u < NT; u += 2) {
    TILE(0, u,     aC, bC, aN, bN);
    TILE(1, u + 1, aN, bN, aC, bC);
  }

  // C/D layout: col = lane&15, row = (lane>>4)*4 + j
  // out row = m0 + wr*128 + mf*16 + (lane>>4)*4 + j
  // out col = n0 + wc*64  + nf*16 + (lane&15)
  float* Cp = C + (size_t)(m0 + wr * 128 + ((lane >> 4) << 2)) * N
                + n0 + wc * 64 + (lane & 15);
#pragma unroll
  for (int mf = 0; mf < 8; mf++)
#pragma unroll
    for (int nf = 0; nf < 4; nf++)
#pragma unroll
      for (int j = 0; j < 4; j++)
        Cp[(size_t)(mf * 16 + j) * N + nf * 16] = acc[mf][nf][j];
}

// ---------------- exact fp32 fallback (only if ws too small) ---------------
__global__ __launch_bounds__(256) void naive_gemm(const float* __restrict__ x,
                                                  const int* __restrict__ qw,
                                                  const int* __restrict__ qz,
                                                  const float* __restrict__ sc,
                                                  float* __restrict__ out) {
  __shared__ float xs[IN_F];
  int m = blockIdx.y;
  int n = blockIdx.x * 256 + threadIdx.x;
  for (int i = threadIdx.x; i < IN_F; i += 256) xs[i] = x[(size_t)m * IN_F + i];
  __syncthreads();
  float acc = 0.f;
  const int* qrow = qw + (size_t)n * (IN_F / 2);
  for (int g = 0; g < NGROUP; g++) {
    float z = (float)qz[n * NGROUP + g];
    float s = sc[n * NGROUP + g];
    for (int t = 0; t < 64; t++) {
      int q = qrow[g * 64 + t];
      acc += xs[g * 128 + 2 * t] * ((float)(q & 15) - z) * s;
      acc += xs[g * 128 + 2 * t + 1] * ((float)((q >> 4) & 15) - z) * s;
    }
  }
  out[(size_t)m * OUT_F + n] = acc;
}

extern "C" void kernel_launch(void* const* d_in, const int* in_sizes, int n_in,
                              void* d_out, int out_size, void* d_ws, size_t ws_size,
                              hipStream_t stream) {
  const float* x  = (const float*)d_in[0];
  const int*   qw = (const int*)d_in[1];
  const int*   qz = (const int*)d_in[2];
  const float* sc = (const float*)d_in[3];
  float* out = (float*)d_out;

  const size_t WBYTES = (size_t)OUT_F * IN_F * 2;
  const size_t XBYTES = (size_t)M_DIM * IN_F * 2;

  if (ws_size >= WBYTES + XBYTES) {
    u16* Wb = (u16*)d_ws;
    u16* Xb = (u16*)((char*)d_ws + WBYTES);
    dequant_w<<<2048, 256, 0, stream>>>(qw, qz, sc, Wb);
    cvt_x<<<2048, 256, 0, stream>>>(x, Xb);
    gemm256<<<(M_DIM / 256) * (OUT_F / 256), 512, 0, stream>>>(Xb, Wb, out);
  } else {
    naive_gemm<<<dim3(OUT_F / 256, M_DIM), 256, 0, stream>>>(x, qw, qz, sc, out);
  }
}